// Round 9
// baseline (289.421 us; speedup 1.0000x reference)
//
#include <hip/hip_runtime.h>
#include <hip/hip_bf16.h>

typedef __hip_bfloat16 bf16;
typedef __attribute__((ext_vector_type(8))) short short8;
typedef __attribute__((ext_vector_type(4))) float f32x4;

#define Bq   2
#define Tq   2048
#define Dq   2048
#define NHq  16
#define HDq  48
#define LATq 256
#define NLHq 8
#define QN   (NHq * HDq)    // 768
#define KVN  (NLHq * HDq)   // 384

__device__ __forceinline__ unsigned short f2u(float x) {
    __hip_bfloat16 h = __float2bfloat16(x);
    return *reinterpret_cast<unsigned short*>(&h);
}
__device__ __forceinline__ float u2f(unsigned short u) {
    return __uint_as_float((unsigned)u << 16);
}
__device__ __forceinline__ unsigned pk2(float a, float b) {
    return (unsigned)f2u(a) | ((unsigned)f2u(b) << 16);
}

// ---- x fp32 -> bf16, 8 elems/thread ------------------------------------------
__global__ void __launch_bounds__(256)
cvt_x(const float* __restrict__ in, bf16* __restrict__ out) {
    const size_t i = ((size_t)blockIdx.x * 256 + threadIdx.x) * 8;
    const float4 a = *(const float4*)&in[i];
    const float4 b = *(const float4*)&in[i + 4];
    uint4 u;
    u.x = pk2(a.x, a.y); u.y = pk2(a.z, a.w);
    u.z = pk2(b.x, b.y); u.w = pk2(b.z, b.w);
    *(uint4*)&out[i] = u;
}

// ---- W fp32 [K][N] -> WT bf16 [N][K], 32x32 LDS tiles -------------------------
__global__ void __launch_bounds__(256)
tr_w(const float* __restrict__ W, bf16* __restrict__ WT, int K, int N) {
    __shared__ float ts[32][33];
    const int n0 = blockIdx.x * 32, k0 = blockIdx.y * 32;
    const int t = threadIdx.x;
    const int r = t >> 3, c4 = (t & 7) * 4;
    const float4 v = *(const float4*)&W[(size_t)(k0 + r) * N + n0 + c4];
    ts[r][c4] = v.x; ts[r][c4 + 1] = v.y; ts[r][c4 + 2] = v.z; ts[r][c4 + 3] = v.w;
    __syncthreads();
    const unsigned u0 = pk2(ts[c4][r], ts[c4 + 1][r]);
    const unsigned u1 = pk2(ts[c4 + 2][r], ts[c4 + 3][r]);
    *(uint2*)&WT[(size_t)(n0 + r) * K + k0 + c4] = make_uint2(u0, u1);
}

// ==== bf16 GEMM, 128x64 tile, double-buffered LDS, 1 barrier/k-step ===========
// (unchanged from R8 — verified 279 µs total)
template<int MODE>
__global__ void __launch_bounds__(256)
gemm128(const bf16* __restrict__ A, const bf16* __restrict__ BT,
        void* __restrict__ C0v, void* __restrict__ C1v, int K) {
    __shared__ short As[2][128 * 40];
    __shared__ short Bs[2][64 * 40];
    const int t  = threadIdx.x;
    const int m0 = blockIdx.x * 128;
    const int n0 = blockIdx.y * 64;
    const int w  = t >> 6;
    const int wm = (w & 1) * 64;
    const int wn = (w >> 1) * 32;
    const int lr = t & 15;
    const int quad = (t >> 4) & 3;
    const int sr = t >> 2, sc = t & 3;          // staging row / 16B chunk

    f32x4 acc[4][2];
    #pragma unroll
    for (int mi = 0; mi < 4; ++mi)
        #pragma unroll
        for (int ni = 0; ni < 2; ++ni) acc[mi][ni] = (f32x4){0.f, 0.f, 0.f, 0.f};

    int aoff[4], boff[2];
    #pragma unroll
    for (int mi = 0; mi < 4; ++mi) aoff[mi] = (wm + mi * 16 + lr) * 40 + quad * 8;
    #pragma unroll
    for (int ni = 0; ni < 2; ++ni) boff[ni] = (wn + ni * 16 + lr) * 40 + quad * 8;

    uint4 pa0, pa1, pb0;
    auto glo = [&](int kt) {
        const int kb = kt * 32 + sc * 8;
        pa0 = *(const uint4*)&A[(size_t)(m0 + sr) * K + kb];
        pa1 = *(const uint4*)&A[(size_t)(m0 + 64 + sr) * K + kb];
        pb0 = *(const uint4*)&BT[(size_t)(n0 + sr) * K + kb];
    };
    auto lwrite = [&](int bb) {
        *(uint4*)&As[bb][sr * 40 + sc * 8] = pa0;
        *(uint4*)&As[bb][(64 + sr) * 40 + sc * 8] = pa1;
        *(uint4*)&Bs[bb][sr * 40 + sc * 8] = pb0;
    };

    const int nk = K / 32;
    glo(0);
    lwrite(0);
    __syncthreads();
    int cur = 0;

    for (int kt = 0; kt < nk; ++kt) {
        const bool pref = (kt + 1 < nk);
        if (pref) glo(kt + 1);
        short8 af[4], bfr[2];
        #pragma unroll
        for (int mi = 0; mi < 4; ++mi) af[mi] = *(const short8*)&As[cur][aoff[mi]];
        #pragma unroll
        for (int ni = 0; ni < 2; ++ni) bfr[ni] = *(const short8*)&Bs[cur][boff[ni]];
        #pragma unroll
        for (int mi = 0; mi < 4; ++mi)
            #pragma unroll
            for (int ni = 0; ni < 2; ++ni)
                acc[mi][ni] = __builtin_amdgcn_mfma_f32_16x16x32_bf16(af[mi], bfr[ni], acc[mi][ni], 0, 0, 0);
        if (pref) lwrite(cur ^ 1);
        __syncthreads();
        cur ^= 1;
    }

    #pragma unroll
    for (int mi = 0; mi < 4; ++mi)
        #pragma unroll
        for (int ni = 0; ni < 2; ++ni) {
            const int col = n0 + wn + ni * 16 + lr;
            #pragma unroll
            for (int r = 0; r < 4; ++r) {
                const int row = m0 + wm + mi * 16 + quad * 4 + r;
                const float v = acc[mi][ni][r];
                if constexpr (MODE == 0) {
                    if (col < QN) ((bf16*)C0v)[(size_t)row * QN + col] = __float2bfloat16(v);
                    else ((float*)C1v)[(size_t)row * LATq + (col - QN)] = v;
                } else if constexpr (MODE == 1) {
                    if (col < KVN) ((bf16*)C0v)[(size_t)row * KVN + col] = __float2bfloat16(v);
                    else ((bf16*)C1v)[(size_t)row * KVN + (col - KVN)] = __float2bfloat16(v);
                } else {
                    ((float*)C0v)[(size_t)row * Dq + col] = v;
                }
            }
        }
}

// ---- lat = rmsnorm(xkv)*wn : [4096,256]fp32 -> bf16. 1 wave per row. ----------
__global__ void __launch_bounds__(256)
mla_kvrms(const float* __restrict__ xkv, const float* __restrict__ wn,
          bf16* __restrict__ lat) {
    const int t = threadIdx.x;
    const int row = blockIdx.x * 4 + (t >> 6);
    const int lane = t & 63;
    const float4 v = *(const float4*)&xkv[(size_t)row * LATq + lane * 4];
    float ss = v.x * v.x + v.y * v.y + v.z * v.z + v.w * v.w;
    ss += __shfl_xor(ss, 1);  ss += __shfl_xor(ss, 2);  ss += __shfl_xor(ss, 4);
    ss += __shfl_xor(ss, 8);  ss += __shfl_xor(ss, 16); ss += __shfl_xor(ss, 32);
    const float rr = rsqrtf(ss * (1.0f / LATq) + 1e-5f);
    const float4 g = *(const float4*)&wn[lane * 4];
    const unsigned w0 = pk2(v.x * rr * g.x, v.y * rr * g.y);
    const unsigned w1 = pk2(v.z * rr * g.z, v.w * rr * g.w);
    *(uint2*)&lat[(size_t)row * LATq + lane * 4] = make_uint2(w0, w1);
}

// ==== MFMA flash attention, 32 q-rows/block for 4 blocks/CU ===================
// R8 had grid 512 = 2 blocks/CU = 2 waves/SIMD -> latency chains fully exposed
// (Occupancy 11.8%). Now each block owns 32 q-rows of one (b,g): wave w = head
// 2g+(w&1), rows (w>>1)*16 (ONE 16-row subtile/wave -> half the per-thread
// softmax VALU, half the acc state). Grid (8, 64, 2) = 1024 blocks = 4/CU =
// 4 waves/SIMD. LDS: Ks 12.3K + Vt 13.8K + Ps 9.2K = 35.3KB <= 40KB (4/CU).
// K/V staged per block (same 64-key tiles, register-prefetch double-buffer,
// one barrier/tile); staging doubles but is L2-resident. qy = (tile u, half):
// u pairing + b-complement keeps per-CU work balanced.
__global__ void __launch_bounds__(256)
mla_attn(const bf16* __restrict__ q, const bf16* __restrict__ kk,
         const bf16* __restrict__ vv, bf16* __restrict__ ao) {
    __shared__ __align__(16) short Ks[2][64 * 48];
    __shared__ __align__(16) short Vt[2][48 * 72];
    __shared__ __align__(16) short Ps[4][16 * 72];
    const int t    = threadIdx.x;
    const int g    = blockIdx.x;
    const int qy   = blockIdx.y;
    const int b    = blockIdx.z;
    const int u    = qy >> 1;
    const int half = (qy & 1) * 32;
    const int qt0  = (u < 16) ? (u << 1) : (63 - (u << 1));
    const int qt   = b ? (31 - qt0) : qt0;
    const int w    = t >> 6;
    const int lane = t & 63;
    const int lr   = t & 15;
    const int quad = (t >> 4) & 3;
    const int hh   = w & 1;
    const int rh   = w >> 1;
    const int h    = g * 2 + hh;
    const float scale = 0.14433756729740643f;   // 1/sqrt(48)
    const short8 z8 = {0, 0, 0, 0, 0, 0, 0, 0};

    // Q fragment (B-operand): lane holds Q[q = lr][d = ks*32 + quad*8 + j]
    const int qloc = half + rh * 16 + lr;       // row within the 64-row tile
    const int qg   = qt * 64 + qloc;            // global row
    const bf16* qr = q + (size_t)(b * Tq + qg) * QN + h * HDq;
    short8 qf0 = *(const short8*)(qr + quad * 8);
    const short8 q1 = *(const short8*)(qr + 32 + (quad & 1) * 8);
    short8 qf1 = (quad < 2) ? q1 : z8;

    const bf16* kb = kk + (size_t)b * Tq * KVN + g * HDq;
    const bf16* vb = vv + (size_t)b * Tq * KVN + g * HDq;

    float m = -1e30f, l = 0.f;
    f32x4 acc[3];
    #pragma unroll
    for (int dm = 0; dm < 3; ++dm) acc[dm] = (f32x4){0.f, 0.f, 0.f, 0.f};

    short* Pw = &Ps[w][0];
    uint4 pre[3];

    // staging roles: waves 0,1 -> K (384 uint4 tasks); waves 2,3 -> V^T.
    auto issue = [&](int tl) {
        #pragma unroll
        for (int r = 0; r < 3; ++r) {
            if (w < 2) {
                const int idx = (w * 3 + r) * 64 + lane;
                const int row = idx / 6, ch = idx - row * 6;
                pre[r] = *(const uint4*)(kb + (size_t)(tl * 64 + row) * KVN + ch * 8);
            } else {
                const int idx = ((w - 2) * 3 + r) * 64 + lane;
                const int kp = idx & 31, hc = idx >> 5;
                const bf16* src = vb + (size_t)(tl * 64 + 2 * kp) * KVN + hc * 4;
                const uint2 a2 = *(const uint2*)src;
                const uint2 b2 = *(const uint2*)(src + KVN);
                pre[r].x = a2.x; pre[r].y = a2.y; pre[r].z = b2.x; pre[r].w = b2.y;
            }
        }
    };
    auto lwrite = [&](int bb) {
        #pragma unroll
        for (int r = 0; r < 3; ++r) {
            if (w < 2) {
                const int idx = (w * 3 + r) * 64 + lane;
                const int row = idx / 6, ch = idx - row * 6;
                *(uint4*)&Ks[bb][row * 48 + ch * 8] = pre[r];
            } else {
                const int idx = ((w - 2) * 3 + r) * 64 + lane;
                const int kp = idx & 31, hc = idx >> 5;
                const unsigned short* uu = (const unsigned short*)&pre[r];
                #pragma unroll
                for (int j = 0; j < 4; ++j)
                    *(unsigned*)&Vt[bb][(hc * 4 + j) * 72 + 2 * kp] =
                        (unsigned)uu[j] | ((unsigned)uu[4 + j] << 16);
            }
        }
    };

    issue(0);
    lwrite(0);
    __syncthreads();
    int cur = 0;

    for (int tl = 0; tl <= qt; ++tl) {
        const bool pref = (tl < qt);
        if (pref) issue(tl + 1);

        // S^T[key][q] = K·Q^T : lane holds key = mt*16 + quad*4 + r, q = lr
        f32x4 sc[4];
        #pragma unroll
        for (int mt = 0; mt < 4; ++mt) {
            const short8 k0 = *(const short8*)&Ks[cur][(mt * 16 + lr) * 48 + quad * 8];
            const short8 k1v = *(const short8*)&Ks[cur][(mt * 16 + lr) * 48 + 32 + (quad & 1) * 8];
            const short8 k1 = (quad < 2) ? k1v : z8;
            f32x4 s = (f32x4){0.f, 0.f, 0.f, 0.f};
            s = __builtin_amdgcn_mfma_f32_16x16x32_bf16(k0, qf0, s, 0, 0, 0);
            s = __builtin_amdgcn_mfma_f32_16x16x32_bf16(k1, qf1, s, 0, 0, 0);
            sc[mt] = s;
        }
        if (tl == qt) {                         // diagonal tile: mask key > q
            #pragma unroll
            for (int mt = 0; mt < 4; ++mt)
                #pragma unroll
                for (int r = 0; r < 4; ++r)
                    if (mt * 16 + quad * 4 + r > qloc) sc[mt][r] = -1e30f;
        }
        float mx = -1e30f;
        #pragma unroll
        for (int mt = 0; mt < 4; ++mt)
            #pragma unroll
            for (int r = 0; r < 4; ++r) mx = fmaxf(mx, sc[mt][r]);
        mx = fmaxf(mx, __shfl_xor(mx, 16));
        mx = fmaxf(mx, __shfl_xor(mx, 32));
        const float mn = fmaxf(m, mx * scale);
        const float f  = __expf(m - mn);
        m = mn;
        float rs = 0.f;
        #pragma unroll
        for (int mt = 0; mt < 4; ++mt)
            #pragma unroll
            for (int r = 0; r < 4; ++r) {
                const float p = u2f(f2u(__expf(fmaf(sc[mt][r], scale, -mn))));
                sc[mt][r] = p;                  // bf16-rounded weight
                rs += p;
            }
        rs += __shfl_xor(rs, 16);
        rs += __shfl_xor(rs, 32);
        l = l * f + rs;
        #pragma unroll
        for (int dm = 0; dm < 3; ++dm)
            #pragma unroll
            for (int r = 0; r < 4; ++r) acc[dm][r] *= f;
        // pack P to per-wave scratch: Pw[q=lr][key], key pairs -> u32
        #pragma unroll
        for (int mt = 0; mt < 4; ++mt) {
            unsigned* pw = (unsigned*)&Pw[lr * 72 + mt * 16 + quad * 4];
            pw[0] = pk2(sc[mt][0], sc[mt][1]);
            pw[1] = pk2(sc[mt][2], sc[mt][3]);
        }
        // B-frag read-back: lane holds P[q=lr][key = ks*32 + quad*8 + j]
        const short8 pf0 = *(const short8*)&Pw[lr * 72 + quad * 8];
        const short8 pf1 = *(const short8*)&Pw[lr * 72 + 32 + quad * 8];
        // O^T[d][q] += V^T·P^T : lane accumulates d = dm*16 + quad*4 + r, q = lr
        #pragma unroll
        for (int dm = 0; dm < 3; ++dm) {
            const short8 v0 = *(const short8*)&Vt[cur][(dm * 16 + lr) * 72 + quad * 8];
            const short8 v1 = *(const short8*)&Vt[cur][(dm * 16 + lr) * 72 + 32 + quad * 8];
            acc[dm] = __builtin_amdgcn_mfma_f32_16x16x32_bf16(v0, pf0, acc[dm], 0, 0, 0);
            acc[dm] = __builtin_amdgcn_mfma_f32_16x16x32_bf16(v1, pf1, acc[dm], 0, 0, 0);
        }

        if (pref) lwrite(cur ^ 1);              // overlapped with compute
        __syncthreads();
        cur ^= 1;
    }

    const float inv = 1.0f / l;
    bf16* orow = ao + (size_t)(b * Tq + qg) * QN + h * HDq;
    #pragma unroll
    for (int dm = 0; dm < 3; ++dm) {
        const unsigned w0 = pk2(acc[dm][0] * inv, acc[dm][1] * inv);
        const unsigned w1 = pk2(acc[dm][2] * inv, acc[dm][3] * inv);
        *(uint2*)(orow + dm * 16 + quad * 4) = make_uint2(w0, w1);
    }
}

extern "C" void kernel_launch(void* const* d_in, const int* in_sizes, int n_in,
                              void* d_out, int out_size, void* d_ws, size_t ws_size,
                              hipStream_t stream) {
    const float* x   = (const float*)d_in[0];
    // d_in[1]: causal mask — static tril, applied analytically in mla_attn
    const float* Wq  = (const float*)d_in[2];
    const float* Wkv = (const float*)d_in[3];
    const float* wn  = (const float*)d_in[4];
    const float* Wk  = (const float*)d_in[5];
    const float* Wv  = (const float*)d_in[6];
    const float* Wo  = (const float*)d_in[7];
    float* out = (float*)d_out;

    const int M = Bq * Tq;                          // 4096
    // d_out staging (all dead before oproj's final write; exactly 33,554,432 B):
    //   [0        : 16.78M)  xb     bf16 [4096 x 2048]  (dead after gemm_qkv)
    //   [16.78M   : 23.07M)  q      bf16 [4096 x 768]
    //   [23.07M   : 27.26M)  xkv    fp32 [4096 x 256]
    //   [27.26M   : 29.36M)  lat    bf16 [4096 x 256]
    //   [29.36M   : 33.55M)  WqkvT  bf16 [1024 x 2048]  (rows 0-767 Wq, 768+ Wkv)
    //   [WkT;WvT] bf16 [768 x 256] reuses xb region after gemm_qkv (stream-ord).
    char* ob = (char*)d_out;
    bf16*  xb    = (bf16*)ob;
    bf16*  qws   = (bf16*)(ob + 16777216);
    float* xkv   = (float*)(ob + 23068672);
    bf16*  latb  = (bf16*)(ob + 27262976);
    bf16*  WqkvT = (bf16*)(ob + 29360128);
    bf16*  WkvpT = (bf16*)ob;                       // after gemm_qkv
    // ws: k bf16 3.15M | v bf16 3.15M | ao bf16 6.29M; WoT reuses k after attn.
    bf16*  kws = (bf16*)d_ws;
    bf16*  vws = kws + (size_t)M * KVN;
    bf16*  aob = vws + (size_t)M * KVN;
    bf16*  WoT = (bf16*)d_ws;                       // after attn

    cvt_x <<<4096, 256, 0, stream>>>(x, xb);
    tr_w  <<<dim3(QN / 32, Dq / 32), 256, 0, stream>>>(Wq, WqkvT, Dq, QN);
    tr_w  <<<dim3(LATq / 32, Dq / 32), 256, 0, stream>>>(Wkv, WqkvT + (size_t)QN * Dq, Dq, LATq);
    gemm128<0> <<<dim3(M / 128, 1024 / 64), 256, 0, stream>>>(xb, WqkvT, qws, xkv, Dq);
    tr_w  <<<dim3(KVN / 32, LATq / 32), 256, 0, stream>>>(Wk, WkvpT, LATq, KVN);
    tr_w  <<<dim3(KVN / 32, LATq / 32), 256, 0, stream>>>(Wv, WkvpT + (size_t)KVN * LATq, LATq, KVN);
    mla_kvrms <<<M / 4, 256, 0, stream>>>(xkv, wn, latb);
    gemm128<1> <<<dim3(M / 128, 768 / 64), 256, 0, stream>>>(latb, WkvpT, kws, vws, LATq);
    mla_attn <<<dim3(NLHq, 64, Bq), 256, 0, stream>>>(qws, kws, vws, aob);
    tr_w  <<<dim3(Dq / 32, QN / 32), 256, 0, stream>>>(Wo, WoT, QN, Dq);
    gemm128<2> <<<dim3(M / 128, Dq / 64), 256, 0, stream>>>(aob, WoT, out, nullptr, QN);
}

// Round 10
// 260.147 us; speedup vs baseline: 1.1125x; 1.1125x over previous
//
#include <hip/hip_runtime.h>
#include <hip/hip_bf16.h>

typedef __hip_bfloat16 bf16;
typedef __attribute__((ext_vector_type(8))) short short8;
typedef __attribute__((ext_vector_type(4))) float f32x4;

#define Bq   2
#define Tq   2048
#define Dq   2048
#define NHq  16
#define HDq  48
#define LATq 256
#define NLHq 8
#define QN   (NHq * HDq)    // 768
#define KVN  (NLHq * HDq)   // 384

__device__ __forceinline__ unsigned short f2u(float x) {
    __hip_bfloat16 h = __float2bfloat16(x);
    return *reinterpret_cast<unsigned short*>(&h);
}
__device__ __forceinline__ float u2f(unsigned short u) {
    return __uint_as_float((unsigned)u << 16);
}
__device__ __forceinline__ unsigned pk2(float a, float b) {
    return (unsigned)f2u(a) | ((unsigned)f2u(b) << 16);
}

// ---- x fp32 -> bf16, 8 elems/thread ------------------------------------------
__global__ void __launch_bounds__(256)
cvt_x(const float* __restrict__ in, bf16* __restrict__ out) {
    const size_t i = ((size_t)blockIdx.x * 256 + threadIdx.x) * 8;
    const float4 a = *(const float4*)&in[i];
    const float4 b = *(const float4*)&in[i + 4];
    uint4 u;
    u.x = pk2(a.x, a.y); u.y = pk2(a.z, a.w);
    u.z = pk2(b.x, b.y); u.w = pk2(b.z, b.w);
    *(uint4*)&out[i] = u;
}

// ---- W fp32 [K][N] -> WT bf16 [N][K], 32x32 LDS tiles -------------------------
__global__ void __launch_bounds__(256)
tr_w(const float* __restrict__ W, bf16* __restrict__ WT, int K, int N) {
    __shared__ float ts[32][33];
    const int n0 = blockIdx.x * 32, k0 = blockIdx.y * 32;
    const int t = threadIdx.x;
    const int r = t >> 3, c4 = (t & 7) * 4;
    const float4 v = *(const float4*)&W[(size_t)(k0 + r) * N + n0 + c4];
    ts[r][c4] = v.x; ts[r][c4 + 1] = v.y; ts[r][c4 + 2] = v.z; ts[r][c4 + 3] = v.w;
    __syncthreads();
    const unsigned u0 = pk2(ts[c4][r], ts[c4 + 1][r]);
    const unsigned u1 = pk2(ts[c4 + 2][r], ts[c4 + 3][r]);
    *(uint2*)&WT[(size_t)(n0 + r) * K + k0 + c4] = make_uint2(u0, u1);
}

// ==== bf16 GEMM, 128x64 tile, double-buffered LDS, 1 barrier/k-step ===========
// (unchanged from R8 — verified 279 µs total)
template<int MODE>
__global__ void __launch_bounds__(256)
gemm128(const bf16* __restrict__ A, const bf16* __restrict__ BT,
        void* __restrict__ C0v, void* __restrict__ C1v, int K) {
    __shared__ short As[2][128 * 40];
    __shared__ short Bs[2][64 * 40];
    const int t  = threadIdx.x;
    const int m0 = blockIdx.x * 128;
    const int n0 = blockIdx.y * 64;
    const int w  = t >> 6;
    const int wm = (w & 1) * 64;
    const int wn = (w >> 1) * 32;
    const int lr = t & 15;
    const int quad = (t >> 4) & 3;
    const int sr = t >> 2, sc = t & 3;          // staging row / 16B chunk

    f32x4 acc[4][2];
    #pragma unroll
    for (int mi = 0; mi < 4; ++mi)
        #pragma unroll
        for (int ni = 0; ni < 2; ++ni) acc[mi][ni] = (f32x4){0.f, 0.f, 0.f, 0.f};

    int aoff[4], boff[2];
    #pragma unroll
    for (int mi = 0; mi < 4; ++mi) aoff[mi] = (wm + mi * 16 + lr) * 40 + quad * 8;
    #pragma unroll
    for (int ni = 0; ni < 2; ++ni) boff[ni] = (wn + ni * 16 + lr) * 40 + quad * 8;

    uint4 pa0, pa1, pb0;
    auto glo = [&](int kt) {
        const int kb = kt * 32 + sc * 8;
        pa0 = *(const uint4*)&A[(size_t)(m0 + sr) * K + kb];
        pa1 = *(const uint4*)&A[(size_t)(m0 + 64 + sr) * K + kb];
        pb0 = *(const uint4*)&BT[(size_t)(n0 + sr) * K + kb];
    };
    auto lwrite = [&](int bb) {
        *(uint4*)&As[bb][sr * 40 + sc * 8] = pa0;
        *(uint4*)&As[bb][(64 + sr) * 40 + sc * 8] = pa1;
        *(uint4*)&Bs[bb][sr * 40 + sc * 8] = pb0;
    };

    const int nk = K / 32;
    glo(0);
    lwrite(0);
    __syncthreads();
    int cur = 0;

    for (int kt = 0; kt < nk; ++kt) {
        const bool pref = (kt + 1 < nk);
        if (pref) glo(kt + 1);
        short8 af[4], bfr[2];
        #pragma unroll
        for (int mi = 0; mi < 4; ++mi) af[mi] = *(const short8*)&As[cur][aoff[mi]];
        #pragma unroll
        for (int ni = 0; ni < 2; ++ni) bfr[ni] = *(const short8*)&Bs[cur][boff[ni]];
        #pragma unroll
        for (int mi = 0; mi < 4; ++mi)
            #pragma unroll
            for (int ni = 0; ni < 2; ++ni)
                acc[mi][ni] = __builtin_amdgcn_mfma_f32_16x16x32_bf16(af[mi], bfr[ni], acc[mi][ni], 0, 0, 0);
        if (pref) lwrite(cur ^ 1);
        __syncthreads();
        cur ^= 1;
    }

    #pragma unroll
    for (int mi = 0; mi < 4; ++mi)
        #pragma unroll
        for (int ni = 0; ni < 2; ++ni) {
            const int col = n0 + wn + ni * 16 + lr;
            #pragma unroll
            for (int r = 0; r < 4; ++r) {
                const int row = m0 + wm + mi * 16 + quad * 4 + r;
                const float v = acc[mi][ni][r];
                if constexpr (MODE == 0) {
                    if (col < QN) ((bf16*)C0v)[(size_t)row * QN + col] = __float2bfloat16(v);
                    else ((float*)C1v)[(size_t)row * LATq + (col - QN)] = v;
                } else if constexpr (MODE == 1) {
                    if (col < KVN) ((bf16*)C0v)[(size_t)row * KVN + col] = __float2bfloat16(v);
                    else ((bf16*)C1v)[(size_t)row * KVN + (col - KVN)] = __float2bfloat16(v);
                } else {
                    ((float*)C0v)[(size_t)row * Dq + col] = v;
                }
            }
        }
}

// ---- lat = rmsnorm(xkv)*wn : [4096,256]fp32 -> bf16. 1 wave per row. ----------
__global__ void __launch_bounds__(256)
mla_kvrms(const float* __restrict__ xkv, const float* __restrict__ wn,
          bf16* __restrict__ lat) {
    const int t = threadIdx.x;
    const int row = blockIdx.x * 4 + (t >> 6);
    const int lane = t & 63;
    const float4 v = *(const float4*)&xkv[(size_t)row * LATq + lane * 4];
    float ss = v.x * v.x + v.y * v.y + v.z * v.z + v.w * v.w;
    ss += __shfl_xor(ss, 1);  ss += __shfl_xor(ss, 2);  ss += __shfl_xor(ss, 4);
    ss += __shfl_xor(ss, 8);  ss += __shfl_xor(ss, 16); ss += __shfl_xor(ss, 32);
    const float rr = rsqrtf(ss * (1.0f / LATq) + 1e-5f);
    const float4 g = *(const float4*)&wn[lane * 4];
    const unsigned w0 = pk2(v.x * rr * g.x, v.y * rr * g.y);
    const unsigned w1 = pk2(v.z * rr * g.z, v.w * rr * g.w);
    *(uint2*)&lat[(size_t)row * LATq + lane * 4] = make_uint2(w0, w1);
}

// ==== MFMA flash attention: 8 waves/block, R8 staging amortization ============
// R8 (4 waves, 2 subtiles/wave serial): 8 waves/CU -> latency exposed, 85.6us.
// R9 (more blocks): doubled staging -> 101.9us. This: keep R8's 64-row/2-head
// block (K/V staged ONCE per block, same bytes as R8) but run the two 16-row
// subtiles as SEPARATE waves: 512 thr / 8 waves; wave w = head 2g+(w&1),
// subtile rh=w>>1 (rows rh*16..+16). Grid (8,32,2) = 512 blocks = 2/CU ->
// 16 waves/CU = 4 waves/SIMD. Staging: waves 0-1 K, 2-3 V^T (R8 code); waves
// 4-7 compute-only. LDS 44.5KB (Ks 12.3K + Vt 13.8K + Ps 8x16x72 = 18.4K).
__global__ void __launch_bounds__(512)
mla_attn(const bf16* __restrict__ q, const bf16* __restrict__ kk,
         const bf16* __restrict__ vv, bf16* __restrict__ ao) {
    __shared__ __align__(16) short Ks[2][64 * 48];
    __shared__ __align__(16) short Vt[2][48 * 72];
    __shared__ __align__(16) short Ps[8][16 * 72];
    const int t    = threadIdx.x;
    const int g    = blockIdx.x;
    const int qy   = blockIdx.y;
    const int b    = blockIdx.z;
    const int qt0  = (qy < 16) ? (qy << 1) : (63 - (qy << 1));
    const int qt   = b ? (31 - qt0) : qt0;
    const int w    = t >> 6;                    // 0..7
    const int lane = t & 63;
    const int lr   = t & 15;
    const int quad = (t >> 4) & 3;
    const int hh   = w & 1;
    const int rh   = w >> 1;                    // 0..3: 16-row subtile
    const int h    = g * 2 + hh;
    const float scale = 0.14433756729740643f;   // 1/sqrt(48)
    const short8 z8 = {0, 0, 0, 0, 0, 0, 0, 0};

    // Q fragment (B-operand): lane holds Q[q = lr][d = ks*32 + quad*8 + j]
    const int qloc = rh * 16 + lr;              // row within the 64-row tile
    const int qg   = qt * 64 + qloc;            // global row
    const bf16* qr = q + (size_t)(b * Tq + qg) * QN + h * HDq;
    short8 qf0 = *(const short8*)(qr + quad * 8);
    const short8 q1 = *(const short8*)(qr + 32 + (quad & 1) * 8);
    short8 qf1 = (quad < 2) ? q1 : z8;

    const bf16* kb = kk + (size_t)b * Tq * KVN + g * HDq;
    const bf16* vb = vv + (size_t)b * Tq * KVN + g * HDq;

    float m = -1e30f, l = 0.f;
    f32x4 acc[3];
    #pragma unroll
    for (int dm = 0; dm < 3; ++dm) acc[dm] = (f32x4){0.f, 0.f, 0.f, 0.f};

    short* Pw = &Ps[w][0];
    uint4 pre[3];

    // staging roles: waves 0,1 -> K (384 uint4 tasks); waves 2,3 -> V^T;
    // waves 4-7 compute-only (wait at barrier while stagers write).
    auto issue = [&](int tl) {
        if (w >= 4) return;
        #pragma unroll
        for (int r = 0; r < 3; ++r) {
            if (w < 2) {
                const int idx = (w * 3 + r) * 64 + lane;
                const int row = idx / 6, ch = idx - row * 6;
                pre[r] = *(const uint4*)(kb + (size_t)(tl * 64 + row) * KVN + ch * 8);
            } else {
                const int idx = ((w - 2) * 3 + r) * 64 + lane;
                const int kp = idx & 31, hc = idx >> 5;
                const bf16* src = vb + (size_t)(tl * 64 + 2 * kp) * KVN + hc * 4;
                const uint2 a2 = *(const uint2*)src;
                const uint2 b2 = *(const uint2*)(src + KVN);
                pre[r].x = a2.x; pre[r].y = a2.y; pre[r].z = b2.x; pre[r].w = b2.y;
            }
        }
    };
    auto lwrite = [&](int bb) {
        if (w >= 4) return;
        #pragma unroll
        for (int r = 0; r < 3; ++r) {
            if (w < 2) {
                const int idx = (w * 3 + r) * 64 + lane;
                const int row = idx / 6, ch = idx - row * 6;
                *(uint4*)&Ks[bb][row * 48 + ch * 8] = pre[r];
            } else {
                const int idx = ((w - 2) * 3 + r) * 64 + lane;
                const int kp = idx & 31, hc = idx >> 5;
                const unsigned short* uu = (const unsigned short*)&pre[r];
                #pragma unroll
                for (int j = 0; j < 4; ++j)
                    *(unsigned*)&Vt[bb][(hc * 4 + j) * 72 + 2 * kp] =
                        (unsigned)uu[j] | ((unsigned)uu[4 + j] << 16);
            }
        }
    };

    issue(0);
    lwrite(0);
    __syncthreads();
    int cur = 0;

    for (int tl = 0; tl <= qt; ++tl) {
        const bool pref = (tl < qt);
        if (pref) issue(tl + 1);

        // S^T[key][q] = K·Q^T : lane holds key = mt*16 + quad*4 + r, q = lr
        f32x4 sc[4];
        #pragma unroll
        for (int mt = 0; mt < 4; ++mt) {
            const short8 k0 = *(const short8*)&Ks[cur][(mt * 16 + lr) * 48 + quad * 8];
            const short8 k1v = *(const short8*)&Ks[cur][(mt * 16 + lr) * 48 + 32 + (quad & 1) * 8];
            const short8 k1 = (quad < 2) ? k1v : z8;
            f32x4 s = (f32x4){0.f, 0.f, 0.f, 0.f};
            s = __builtin_amdgcn_mfma_f32_16x16x32_bf16(k0, qf0, s, 0, 0, 0);
            s = __builtin_amdgcn_mfma_f32_16x16x32_bf16(k1, qf1, s, 0, 0, 0);
            sc[mt] = s;
        }
        if (tl == qt) {                         // diagonal tile: mask key > q
            #pragma unroll
            for (int mt = 0; mt < 4; ++mt)
                #pragma unroll
                for (int r = 0; r < 4; ++r)
                    if (mt * 16 + quad * 4 + r > qloc) sc[mt][r] = -1e30f;
        }
        float mx = -1e30f;
        #pragma unroll
        for (int mt = 0; mt < 4; ++mt)
            #pragma unroll
            for (int r = 0; r < 4; ++r) mx = fmaxf(mx, sc[mt][r]);
        mx = fmaxf(mx, __shfl_xor(mx, 16));
        mx = fmaxf(mx, __shfl_xor(mx, 32));
        const float mn = fmaxf(m, mx * scale);
        const float f  = __expf(m - mn);
        m = mn;
        float rs = 0.f;
        #pragma unroll
        for (int mt = 0; mt < 4; ++mt)
            #pragma unroll
            for (int r = 0; r < 4; ++r) {
                const float p = u2f(f2u(__expf(fmaf(sc[mt][r], scale, -mn))));
                sc[mt][r] = p;                  // bf16-rounded weight
                rs += p;
            }
        rs += __shfl_xor(rs, 16);
        rs += __shfl_xor(rs, 32);
        l = l * f + rs;
        #pragma unroll
        for (int dm = 0; dm < 3; ++dm)
            #pragma unroll
            for (int r = 0; r < 4; ++r) acc[dm][r] *= f;
        // pack P to per-wave scratch: Pw[q=lr][key], key pairs -> u32
        #pragma unroll
        for (int mt = 0; mt < 4; ++mt) {
            unsigned* pw = (unsigned*)&Pw[lr * 72 + mt * 16 + quad * 4];
            pw[0] = pk2(sc[mt][0], sc[mt][1]);
            pw[1] = pk2(sc[mt][2], sc[mt][3]);
        }
        // B-frag read-back: lane holds P[q=lr][key = ks*32 + quad*8 + j]
        const short8 pf0 = *(const short8*)&Pw[lr * 72 + quad * 8];
        const short8 pf1 = *(const short8*)&Pw[lr * 72 + 32 + quad * 8];
        // O^T[d][q] += V^T·P^T : lane accumulates d = dm*16 + quad*4 + r, q = lr
        #pragma unroll
        for (int dm = 0; dm < 3; ++dm) {
            const short8 v0 = *(const short8*)&Vt[cur][(dm * 16 + lr) * 72 + quad * 8];
            const short8 v1 = *(const short8*)&Vt[cur][(dm * 16 + lr) * 72 + 32 + quad * 8];
            acc[dm] = __builtin_amdgcn_mfma_f32_16x16x32_bf16(v0, pf0, acc[dm], 0, 0, 0);
            acc[dm] = __builtin_amdgcn_mfma_f32_16x16x32_bf16(v1, pf1, acc[dm], 0, 0, 0);
        }

        if (pref) lwrite(cur ^ 1);              // overlapped with compute
        __syncthreads();
        cur ^= 1;
    }

    const float inv = 1.0f / l;
    bf16* orow = ao + (size_t)(b * Tq + qg) * QN + h * HDq;
    #pragma unroll
    for (int dm = 0; dm < 3; ++dm) {
        const unsigned w0 = pk2(acc[dm][0] * inv, acc[dm][1] * inv);
        const unsigned w1 = pk2(acc[dm][2] * inv, acc[dm][3] * inv);
        *(uint2*)(orow + dm * 16 + quad * 4) = make_uint2(w0, w1);
    }
}

extern "C" void kernel_launch(void* const* d_in, const int* in_sizes, int n_in,
                              void* d_out, int out_size, void* d_ws, size_t ws_size,
                              hipStream_t stream) {
    const float* x   = (const float*)d_in[0];
    // d_in[1]: causal mask — static tril, applied analytically in mla_attn
    const float* Wq  = (const float*)d_in[2];
    const float* Wkv = (const float*)d_in[3];
    const float* wn  = (const float*)d_in[4];
    const float* Wk  = (const float*)d_in[5];
    const float* Wv  = (const float*)d_in[6];
    const float* Wo  = (const float*)d_in[7];
    float* out = (float*)d_out;

    const int M = Bq * Tq;                          // 4096
    // d_out staging (all dead before oproj's final write; exactly 33,554,432 B):
    //   [0        : 16.78M)  xb     bf16 [4096 x 2048]  (dead after gemm_qkv)
    //   [16.78M   : 23.07M)  q      bf16 [4096 x 768]
    //   [23.07M   : 27.26M)  xkv    fp32 [4096 x 256]
    //   [27.26M   : 29.36M)  lat    bf16 [4096 x 256]
    //   [29.36M   : 33.55M)  WqkvT  bf16 [1024 x 2048]  (rows 0-767 Wq, 768+ Wkv)
    //   [WkT;WvT] bf16 [768 x 256] reuses xb region after gemm_qkv (stream-ord).
    char* ob = (char*)d_out;
    bf16*  xb    = (bf16*)ob;
    bf16*  qws   = (bf16*)(ob + 16777216);
    float* xkv   = (float*)(ob + 23068672);
    bf16*  latb  = (bf16*)(ob + 27262976);
    bf16*  WqkvT = (bf16*)(ob + 29360128);
    bf16*  WkvpT = (bf16*)ob;                       // after gemm_qkv
    // ws: k bf16 3.15M | v bf16 3.15M | ao bf16 6.29M; WoT reuses k after attn.
    bf16*  kws = (bf16*)d_ws;
    bf16*  vws = kws + (size_t)M * KVN;
    bf16*  aob = vws + (size_t)M * KVN;
    bf16*  WoT = (bf16*)d_ws;                       // after attn

    cvt_x <<<4096, 256, 0, stream>>>(x, xb);
    tr_w  <<<dim3(QN / 32, Dq / 32), 256, 0, stream>>>(Wq, WqkvT, Dq, QN);
    tr_w  <<<dim3(LATq / 32, Dq / 32), 256, 0, stream>>>(Wkv, WqkvT + (size_t)QN * Dq, Dq, LATq);
    gemm128<0> <<<dim3(M / 128, 1024 / 64), 256, 0, stream>>>(xb, WqkvT, qws, xkv, Dq);
    tr_w  <<<dim3(KVN / 32, LATq / 32), 256, 0, stream>>>(Wk, WkvpT, LATq, KVN);
    tr_w  <<<dim3(KVN / 32, LATq / 32), 256, 0, stream>>>(Wv, WkvpT + (size_t)KVN * LATq, LATq, KVN);
    mla_kvrms <<<M / 4, 256, 0, stream>>>(xkv, wn, latb);
    gemm128<1> <<<dim3(M / 128, 768 / 64), 256, 0, stream>>>(latb, WkvpT, kws, vws, LATq);
    mla_attn <<<dim3(NLHq, 32, Bq), 512, 0, stream>>>(qws, kws, vws, aob);
    tr_w  <<<dim3(Dq / 32, QN / 32), 256, 0, stream>>>(Wo, WoT, QN, Dq);
    gemm128<2> <<<dim3(M / 128, Dq / 64), 256, 0, stream>>>(aob, WoT, out, nullptr, QN);
}